// Round 6
// baseline (368.473 us; speedup 1.0000x reference)
//
#include <hip/hip_runtime.h>
#include <hip/hip_cooperative_groups.h>

namespace cg = cooperative_groups;

// simpleGCN_SAGPOOL on MI355X (gfx950) — single cooperative kernel.
// Structure: edge_index = 320K-edge base graph replicated B=32x with offsets
// (PyG batching) => degree/dis depend only on g = n % G; score = SpMM of the
// base graph against hws in [g][b] layout. Exact k-th largest per graph via
// 3-level (11/11/10 bit) LDS radix refinement on monotone-uint keys.
// R5 profile showed ~48us per tiny dispatch (memset, 1-block scan) =>
// dispatch-overhead-bound. Fuse everything into ONE kernel + grid.sync().

#define GRID_BLOCKS 256
#define BLOCK_THREADS 1024

__global__ __launch_bounds__(1024) void k_fused(
    const float* __restrict__ x, const int* __restrict__ src, const int* __restrict__ dst,
    const float* __restrict__ emb_w, const float* __restrict__ emb_b,
    const float* __restrict__ gcn_w, const float* __restrict__ gcn_b,
    const float* __restrict__ lin_w, const float* __restrict__ lin_b,
    float* __restrict__ out,
    float* __restrict__ hws_t, unsigned int* __restrict__ key_t,
    int* __restrict__ csr, int* __restrict__ cnt, int* __restrict__ rowptr,
    int* __restrict__ wp, float* __restrict__ dis, float* __restrict__ ew_dot,
    int* __restrict__ thr_, int* __restrict__ tneed, int* __restrict__ alleq,
    float* __restrict__ partials,
    int G, int N, int E_PER, int k)
{
    cg::grid_group grid = cg::this_grid();
    __shared__ float smf[8704];            // 34816 B, reused per phase
    int tid = threadIdx.x, bid = blockIdx.x;
    int gtid = bid * BLOCK_THREADS + tid;
    const int gstride = GRID_BLOCKS * BLOCK_THREADS;

    // ---------- P0: zero degree counters; ew_dot[g] = emb_w[g,:].gcn_w ----------
    for (int i = gtid; i < G; i += gstride) cnt[i] = 0;
    {
        const float4* w = (const float4*)gcn_w;
        float4 w0 = w[0], w1 = w[1], w2 = w[2], w3 = w[3];
        for (int g = gtid; g < G; g += gstride) {
            const float4* row = (const float4*)(emb_w + (size_t)g * 16);
            float4 r0 = row[0], r1 = row[1], r2 = row[2], r3 = row[3];
            ew_dot[g] = r0.x*w0.x + r0.y*w0.y + r0.z*w0.z + r0.w*w0.w
                      + r1.x*w1.x + r1.y*w1.y + r1.z*w1.z + r1.w*w1.w
                      + r2.x*w2.x + r2.y*w2.y + r2.z*w2.z + r2.w*w2.w
                      + r3.x*w3.x + r3.y*w3.y + r3.z*w3.z + r3.w*w3.w;
        }
    }
    grid.sync();

    // ---------- P1: base-graph in-degree histogram ----------
    {
        int E4 = E_PER >> 2;
        const int4* dst4 = (const int4*)dst;
        for (int i = gtid; i < E4; i += gstride) {
            int4 d = dst4[i];
            atomicAdd(&cnt[d.x], 1);
            atomicAdd(&cnt[d.y], 1);
            atomicAdd(&cnt[d.z], 1);
            atomicAdd(&cnt[d.w], 1);
        }
    }
    grid.sync();

    // ---------- P2: block 0 scans (rowptr/wp/dis); blocks 1.. compute hw ----------
    if (bid == 0) {
        int* part = (int*)smf;
        int per = (G + BLOCK_THREADS - 1) / BLOCK_THREADS;
        int beg = tid * per;
        int end = beg + per; if (end > G) end = G;
        int s = 0;
        for (int i = beg; i < end; ++i) s += cnt[i];
        part[tid] = s;
        __syncthreads();
        for (int off = 1; off < BLOCK_THREADS; off <<= 1) {
            int v = (tid >= off) ? part[tid - off] : 0;
            __syncthreads();
            part[tid] += v;
            __syncthreads();
        }
        int run = part[tid] - s;
        for (int i = beg; i < end; ++i) {
            rowptr[i] = run;
            wp[i] = run;
            int c = cnt[i];
            dis[i] = rsqrtf(1.0f + (float)c);
            run += c;
        }
        if (tid == BLOCK_THREADS - 1) rowptr[G] = part[BLOCK_THREADS - 1];
    } else {
        float sw = 0.f;
        #pragma unroll
        for (int c = 0; c < 16; ++c) sw += gcn_w[c];
        int gt2 = (bid - 1) * BLOCK_THREADS + tid;
        const int gs2 = (GRID_BLOCKS - 1) * BLOCK_THREADS;
        for (int n = gt2; n < N; n += gs2) {
            int g = n >> 5, b = n & 31;
            hws_t[n] = ew_dot[g] * x[(size_t)b * G + g] + emb_b[g] * sw;
        }
    }
    grid.sync();

    // ---------- P3: fill dst-CSR (atomic cursors) + scale hw by dis ----------
    for (int e = gtid; e < E_PER; e += gstride) {
        int d = dst[e];
        int pos = atomicAdd(&wp[d], 1);
        csr[pos] = src[e];
    }
    for (int n = gtid; n < N; n += gstride) hws_t[n] *= dis[n >> 5];
    grid.sync();

    // ---------- P4: SpMM (one wave per dst node) + self-loop + key ----------
    {
        int wid = gtid >> 6;
        int lane = tid & 63;
        int half = lane >> 5;
        int b = lane & 31;
        const int nw = gstride >> 6;
        float gb = gcn_b[0];
        for (int node = wid; node < G; node += nw) {
            int beg = rowptr[node], end = rowptr[node + 1];
            float acc = 0.f;
            for (int e = beg + half; e < end; e += 2)
                acc += hws_t[((size_t)csr[e] << 5) + b];
            acc += __shfl_down(acc, 32);
            if (lane < 32) {
                float sc = (acc + hws_t[((size_t)node << 5) + b]) * dis[node] + gb;
                unsigned int u = __float_as_uint(sc);
                u = (u & 0x80000000u) ? ~u : (u | 0x80000000u);
                key_t[((size_t)node << 5) + b] = u;
            }
        }
    }
    grid.sync();

    // ---------- P5: per-graph exact k-th threshold (blocks 0..31) ----------
    if (bid < 32) {
        int* hist  = (int*)smf;            // 2048
        int* part  = (int*)smf + 2048;     // 1024
        int* s_sel = (int*)smf + 3072;
        int* s_want= (int*)smf + 3073;
        int b = bid;
        int t = tid;
        if (t == 0) *s_want = k;

        // pass 1: bits 31:21
        hist[t] = 0; hist[t + 1024] = 0;
        __syncthreads();
        for (int g = t; g < G; g += 1024)
            atomicAdd(&hist[key_t[((size_t)g << 5) + b] >> 21], 1);
        __syncthreads();
        int own = hist[2*t] + hist[2*t+1];
        part[t] = own;
        __syncthreads();
        for (int off = 1; off < 1024; off <<= 1) {
            int v = (t + off < 1024) ? part[t + off] : 0;
            __syncthreads();
            part[t] += v;
            __syncthreads();
        }
        int want = *s_want;
        __syncthreads();
        {
            int excl = part[t] - own;
            int hv = hist[2*t+1];
            if (excl < want && want <= excl + hv) { *s_sel = 2*t+1; *s_want = want - excl; }
            excl += hv;
            hv = hist[2*t];
            if (excl < want && want <= excl + hv) { *s_sel = 2*t; *s_want = want - excl; }
        }
        __syncthreads();
        unsigned int sel1 = (unsigned int)*s_sel;

        // pass 2: bits 20:10
        hist[t] = 0; hist[t + 1024] = 0;
        __syncthreads();
        for (int g = t; g < G; g += 1024) {
            unsigned int u = key_t[((size_t)g << 5) + b];
            if ((u >> 21) == sel1) atomicAdd(&hist[(u >> 10) & 2047u], 1);
        }
        __syncthreads();
        own = hist[2*t] + hist[2*t+1];
        part[t] = own;
        __syncthreads();
        for (int off = 1; off < 1024; off <<= 1) {
            int v = (t + off < 1024) ? part[t + off] : 0;
            __syncthreads();
            part[t] += v;
            __syncthreads();
        }
        want = *s_want;
        __syncthreads();
        {
            int excl = part[t] - own;
            int hv = hist[2*t+1];
            if (excl < want && want <= excl + hv) { *s_sel = 2*t+1; *s_want = want - excl; }
            excl += hv;
            hv = hist[2*t];
            if (excl < want && want <= excl + hv) { *s_sel = 2*t; *s_want = want - excl; }
        }
        __syncthreads();
        unsigned int sel2 = (unsigned int)*s_sel;
        unsigned int pref = (sel1 << 11) | sel2;

        // pass 3: bits 9:0
        hist[t] = 0;
        __syncthreads();
        for (int g = t; g < G; g += 1024) {
            unsigned int u = key_t[((size_t)g << 5) + b];
            if ((u >> 10) == pref) atomicAdd(&hist[u & 1023u], 1);
        }
        __syncthreads();
        own = hist[t];
        part[t] = own;
        __syncthreads();
        for (int off = 1; off < 1024; off <<= 1) {
            int v = (t + off < 1024) ? part[t + off] : 0;
            __syncthreads();
            part[t] += v;
            __syncthreads();
        }
        want = *s_want;
        __syncthreads();
        {
            int excl = part[t] - own;
            if (excl < want && want <= excl + own) {
                thr_[b] = (int)((pref << 10) | (unsigned int)t);
                tneed[b] = want - excl;
                alleq[b] = (own == want - excl) ? 1 : 0;
            }
        }
    }
    grid.sync();

    // ---------- P6: accumulate tanh(s)*[x*emb_w, emb_b] over selected ----------
    {
        float (*lred)[32][17] = (float(*)[32][17])smf;   // 16*32*17 floats
        int b = gtid & 31;                  // gstride % 32 == 0 -> constant
        unsigned int T = (unsigned int)thr_[b];
        int tn = tneed[b];
        bool ae = alleq[b] != 0;
        float accA[16];
        #pragma unroll
        for (int c = 0; c < 16; ++c) accA[c] = 0.f;
        float accB = 0.f;

        for (int e = gtid; e < N; e += gstride) {
            unsigned int u = key_t[e];
            bool take = (u > T);
            if (!take && u == T) {
                if (ae) take = true;
                else {  // rare tie path: rank among equals by node index
                    int g = e >> 5;
                    int rank = 0;
                    for (int gg = 0; gg < g; ++gg)
                        rank += (key_t[(size_t)gg * 32 + b] == T) ? 1 : 0;
                    take = (rank < tn);
                }
            }
            if (take) {
                int g = e >> 5;
                unsigned int ub = (u & 0x80000000u) ? (u & 0x7FFFFFFFu) : ~u;
                float sv = __uint_as_float(ub);
                float t = tanhf(sv);
                float tx = t * x[(size_t)b * G + g];
                accB += t * emb_b[g];
                const float4* row = (const float4*)(emb_w + (size_t)g * 16);
                float4 r0 = row[0], r1 = row[1], r2 = row[2], r3 = row[3];
                accA[0] = fmaf(tx, r0.x, accA[0]);  accA[1] = fmaf(tx, r0.y, accA[1]);
                accA[2] = fmaf(tx, r0.z, accA[2]);  accA[3] = fmaf(tx, r0.w, accA[3]);
                accA[4] = fmaf(tx, r1.x, accA[4]);  accA[5] = fmaf(tx, r1.y, accA[5]);
                accA[6] = fmaf(tx, r1.z, accA[6]);  accA[7] = fmaf(tx, r1.w, accA[7]);
                accA[8] = fmaf(tx, r2.x, accA[8]);  accA[9] = fmaf(tx, r2.y, accA[9]);
                accA[10] = fmaf(tx, r2.z, accA[10]); accA[11] = fmaf(tx, r2.w, accA[11]);
                accA[12] = fmaf(tx, r3.x, accA[12]); accA[13] = fmaf(tx, r3.y, accA[13]);
                accA[14] = fmaf(tx, r3.z, accA[14]); accA[15] = fmaf(tx, r3.w, accA[15]);
            }
        }
        // lanes l and l+32 share the same graph b
        #pragma unroll
        for (int c = 0; c < 16; ++c) accA[c] += __shfl_down(accA[c], 32);
        accB += __shfl_down(accB, 32);
        __syncthreads();   // smf free (P5 done for bid<32; others idle since)
        int w = tid >> 6, lane = tid & 63;
        if (lane < 32) {
            #pragma unroll
            for (int c = 0; c < 16; ++c) lred[w][lane][c] = accA[c];
            lred[w][lane][16] = accB;
        }
        __syncthreads();
        if (tid < 544) {
            int bb = tid / 17, c = tid % 17;
            float s = 0.f;
            #pragma unroll
            for (int w2 = 0; w2 < 16; ++w2) s += lred[w2][bb][c];
            partials[(size_t)bid * 544 + tid] = s;
        }
    }
    grid.sync();

    // ---------- P7: reduce partials + 16x16 linear (block 0) ----------
    if (bid == 0) {
        float* red = smf;     // 544 floats
        if (tid < 544) {
            float s = 0.f;
            for (int p = 0; p < GRID_BLOCKS; ++p)
                s += partials[(size_t)p * 544 + tid];
            red[tid] = s;
        }
        __syncthreads();
        if (tid < 512) {
            int b = tid >> 4, j = tid & 15;
            float inv = 1.0f / (float)k;
            float bias = red[b * 17 + 16];
            float o = lin_b[j];
            #pragma unroll
            for (int c = 0; c < 16; ++c)
                o = fmaf((red[b * 17 + c] + bias) * inv, lin_w[j * 16 + c], o);
            out[tid] = o;
        }
    }
}

extern "C" void kernel_launch(void* const* d_in, const int* in_sizes, int n_in,
                              void* d_out, int out_size, void* d_ws, size_t ws_size,
                              hipStream_t stream) {
    const float* x     = (const float*)d_in[0];
    const int*   ei    = (const int*)d_in[1];
    const float* emb_w = (const float*)d_in[3];
    const float* emb_b = (const float*)d_in[4];
    const float* gcn_w = (const float*)d_in[5];
    const float* gcn_b = (const float*)d_in[6];
    const float* lin_w = (const float*)d_in[7];
    const float* lin_b = (const float*)d_in[8];
    float* out = (float*)d_out;

    int N = in_sizes[0];          // 640000
    int E = in_sizes[1] / 2;      // 10240000
    int B = out_size / 16;        // 32
    int G = N / B;                // 20000
    int k = (G + 1) / 2;          // 10000
    int E_PER = E / B;            // 320000 base-graph edges

    const int* src = ei;          // first E_PER entries = base graph
    const int* dst = ei + E;

    int* wsI = (int*)d_ws;
    float* hws_t        = (float*)wsI;                 // N
    unsigned int* key_t = (unsigned int*)(wsI + N);    // N   [g][b] layout
    int* csr            = wsI + 2 * (size_t)N;         // E_PER
    int* cnt            = csr + E_PER;                 // G
    int* rowptr         = cnt + G;                     // G+1
    int* wp             = rowptr + G + 1;              // G
    float* dis          = (float*)(wp + G);            // G
    float* ew_dot       = dis + G;                     // G
    int* thr_           = (int*)(ew_dot + G);          // B
    int* tneed          = thr_ + B;                    // B
    int* alleq          = tneed + B;                   // B
    float* partials     = (float*)(alleq + B);         // 256*544

    void* args[] = {
        (void*)&x, (void*)&src, (void*)&dst,
        (void*)&emb_w, (void*)&emb_b, (void*)&gcn_w, (void*)&gcn_b,
        (void*)&lin_w, (void*)&lin_b, (void*)&out,
        (void*)&hws_t, (void*)&key_t, (void*)&csr, (void*)&cnt, (void*)&rowptr,
        (void*)&wp, (void*)&dis, (void*)&ew_dot,
        (void*)&thr_, (void*)&tneed, (void*)&alleq, (void*)&partials,
        (void*)&G, (void*)&N, (void*)&E_PER, (void*)&k
    };
    hipLaunchCooperativeKernel((void*)k_fused, dim3(GRID_BLOCKS), dim3(BLOCK_THREADS),
                               args, 0, stream);
}

// Round 7
// 151.692 us; speedup vs baseline: 2.4291x; 2.4291x over previous
//
#include <hip/hip_runtime.h>

// simpleGCN_SAGPOOL on MI355X (gfx950) — 5-dispatch pipeline.
// Facts driving the design (R0-R6 measurements):
//  - edge_index = 320K-edge base graph replicated B=32x (PyG batching):
//    degree/dis depend only on g = n % G; score = base-graph SpMM.
//  - memory-side atomics ~32B/op (R0: 316MB writes) -> avoid global atomics.
//  - per-dispatch overhead ~10-12us (R2/R3/R5 arithmetic) -> few dispatches.
//  - grid.sync() costs ~40us on 8 non-coherent XCD L2s (R6) -> NO cooperative.

#define GH 10000   // half bin-range for the 40KB LDS degree histogram (G<=2*GH)

// K1 (32 blocks): chunk = bid>>1 edge range, half = bid&1 bin range.
// LDS partial degree hist (no memset, no global atomics) + ew_dot.
__global__ __launch_bounds__(1024) void k_edh(
    const float* __restrict__ emb_w, const float* __restrict__ gcn_w,
    float* __restrict__ ew_dot,
    const int* __restrict__ dst, int* __restrict__ partial, int G, int E_PER)
{
    __shared__ int h[GH];
    int tid = threadIdx.x, bid = blockIdx.x;
    int chunk = bid >> 1, half = bid & 1;
    int lo = half * GH;
    for (int i = tid; i < GH; i += 1024) h[i] = 0;
    __syncthreads();
    int EC = E_PER >> 4;                       // 16 edge chunks
    int e0 = chunk * EC;
    int e1 = (chunk == 15) ? E_PER : e0 + EC;
    for (int e = e0 + tid; e < e1; e += 1024) {
        int d = dst[e] - lo;
        if ((unsigned)d < (unsigned)GH) atomicAdd(&h[d], 1);
    }
    {
        const float4* w = (const float4*)gcn_w;
        float4 w0 = w[0], w1 = w[1], w2 = w[2], w3 = w[3];
        int g = bid * 1024 + tid;
        if (g < G) {
            const float4* row = (const float4*)(emb_w + (size_t)g * 16);
            float4 r0 = row[0], r1 = row[1], r2 = row[2], r3 = row[3];
            ew_dot[g] = r0.x*w0.x + r0.y*w0.y + r0.z*w0.z + r0.w*w0.w
                      + r1.x*w1.x + r1.y*w1.y + r1.z*w1.z + r1.w*w1.w
                      + r2.x*w2.x + r2.y*w2.y + r2.z*w2.z + r2.w*w2.w
                      + r3.x*w3.x + r3.y*w3.y + r3.z*w3.z + r3.w*w3.w;
        }
    }
    __syncthreads();
    for (int i = tid; i < GH; i += 1024) partial[(size_t)bid * GH + i] = h[i];
}

// K2: block 0: merge partials (coalesced) -> deg -> dis/rowptr/wp + scan;
// blocks 1..255: hw (unscaled) into hws_t [g][b].
__global__ __launch_bounds__(1024) void k_scanhw(
    const int* __restrict__ partial, const float* __restrict__ x,
    const float* __restrict__ emb_b, const float* __restrict__ ew_dot,
    const float* __restrict__ gcn_w,
    int* __restrict__ rowptr, int* __restrict__ wp, float* __restrict__ dis,
    float* __restrict__ hws_t, int G, int N)
{
    int tid = threadIdx.x, bid = blockIdx.x;
    if (bid == 0) {
        __shared__ int part[1024];
        // stage 1: coalesced merge; temp-store deg in rowptr
        for (int i = tid; i < G; i += 1024) {
            int hf = (i >= GH) ? 1 : 0;
            int off = i - hf * GH;
            int d = 0;
            #pragma unroll
            for (int c = 0; c < 16; ++c) d += partial[(size_t)(c * 2 + hf) * GH + off];
            rowptr[i] = d;
            dis[i] = rsqrtf(1.0f + (float)d);
        }
        __syncthreads();
        // stage 2: exclusive scan (per-thread contiguous chunks, L1-resident)
        int per = (G + 1023) >> 10;
        int beg = tid * per;
        int end = beg + per; if (end > G) end = G;
        int s = 0;
        for (int i = beg; i < end; ++i) s += rowptr[i];
        part[tid] = s;
        __syncthreads();
        for (int off = 1; off < 1024; off <<= 1) {
            int v = (tid >= off) ? part[tid - off] : 0;
            __syncthreads();
            part[tid] += v;
            __syncthreads();
        }
        int run = part[tid] - s;
        for (int i = beg; i < end; ++i) {
            int d = rowptr[i];
            rowptr[i] = run;
            wp[i] = run;
            run += d;
        }
        if (tid == 1023) rowptr[G] = part[1023];
    } else {
        float sw = 0.f;
        #pragma unroll
        for (int c = 0; c < 16; ++c) sw += gcn_w[c];
        int n0 = (bid - 1) * 1024 + tid;
        const int gs = 255 * 1024;
        for (int n = n0; n < N; n += gs) {
            int g = n >> 5, b = n & 31;
            hws_t[n] = ew_dot[g] * x[(size_t)b * G + g] + emb_b[g] * sw;
        }
    }
}

// K3: fill dst-CSR (atomic cursors, L2 int atomics) + scale hws by dis
__global__ __launch_bounds__(1024) void k_fillsc(
    const int* __restrict__ src, const int* __restrict__ dst,
    int* __restrict__ wp, int* __restrict__ csr,
    float* __restrict__ hws_t, const float* __restrict__ dis, int E_PER, int N)
{
    int gt = blockIdx.x * 1024 + threadIdx.x;
    int gs = gridDim.x * 1024;
    for (int e = gt; e < E_PER; e += gs) {
        int d = dst[e];
        int pos = atomicAdd(&wp[d], 1);
        csr[pos] = src[e];
    }
    for (int n = gt; n < N; n += gs) hws_t[n] *= dis[n >> 5];
}

// K4: SpMM (one wave per dst node, 64 nodes/block) + self-loop + monotone key,
// LDS-transposed so key_bt is [b][g] (coalesced per-graph reads in k_sel).
__global__ __launch_bounds__(1024) void k_spmm(
    const int* __restrict__ rowptr, const int* __restrict__ csr,
    const float* __restrict__ hws_t, const float* __restrict__ dis,
    const float* __restrict__ gcn_b, unsigned int* __restrict__ key_bt, int G)
{
    __shared__ unsigned int tile[64][33];
    int tid = threadIdx.x;
    int n0 = blockIdx.x * 64;
    int w = tid >> 6, lane = tid & 63, half = lane >> 5, b = lane & 31;
    float gb = gcn_b[0];
    #pragma unroll
    for (int r = 0; r < 4; ++r) {
        int node = n0 + r * 16 + w;
        if (node < G) {
            int beg = rowptr[node], end = rowptr[node + 1];
            float acc = 0.f;
            for (int e = beg + half; e < end; e += 2)
                acc += hws_t[((size_t)csr[e] << 5) + b];
            acc += __shfl_down(acc, 32);
            if (lane < 32) {
                float sc = (acc + hws_t[((size_t)node << 5) + b]) * dis[node] + gb;
                unsigned int u = __float_as_uint(sc);
                u = (u & 0x80000000u) ? ~u : (u | 0x80000000u);
                tile[r * 16 + w][b] = u;
            }
        }
    }
    __syncthreads();
    for (int idx = tid; idx < 2048; idx += 1024) {
        int bb = idx >> 6, ln = idx & 63;
        if (n0 + ln < G) key_bt[(size_t)bb * G + n0 + ln] = tile[ln][bb];
    }
}

// K5 (32 blocks, one per graph): exact k-th threshold via 3-level LDS radix
// (bits 31:21, 20:10, 9:0) + accumulate tanh(s)*[x*emb_w, emb_b] + 16x16 linear.
// All global reads coalesced (key_bt[b][g], x[b*G+g]).
__global__ __launch_bounds__(1024) void k_sel(
    const unsigned int* __restrict__ key_bt, const float* __restrict__ x,
    const float* __restrict__ emb_w, const float* __restrict__ emb_b,
    const float* __restrict__ lin_w, const float* __restrict__ lin_b,
    float* __restrict__ out, int G, int k)
{
    __shared__ int hist[2048];
    __shared__ int part[1024];
    __shared__ int s_sel, s_want;
    __shared__ unsigned int s_thr;
    __shared__ int s_tneed, s_alleq;
    int b = blockIdx.x, t = threadIdx.x;
    const unsigned int* kb = key_bt + (size_t)b * G;
    if (t == 0) s_want = k;

    // ---- pass 1: bits 31:21
    hist[t] = 0; hist[t + 1024] = 0;
    __syncthreads();
    for (int g = t; g < G; g += 1024) atomicAdd(&hist[kb[g] >> 21], 1);
    __syncthreads();
    int own = hist[2*t] + hist[2*t+1];
    part[t] = own;
    __syncthreads();
    for (int off = 1; off < 1024; off <<= 1) {
        int v = (t + off < 1024) ? part[t + off] : 0;
        __syncthreads();
        part[t] += v;
        __syncthreads();
    }
    int want = s_want;
    __syncthreads();
    {
        int excl = part[t] - own;
        int hv = hist[2*t+1];
        if (excl < want && want <= excl + hv) { s_sel = 2*t+1; s_want = want - excl; }
        excl += hv;
        hv = hist[2*t];
        if (excl < want && want <= excl + hv) { s_sel = 2*t; s_want = want - excl; }
    }
    __syncthreads();
    unsigned int sel1 = (unsigned int)s_sel;

    // ---- pass 2: bits 20:10
    hist[t] = 0; hist[t + 1024] = 0;
    __syncthreads();
    for (int g = t; g < G; g += 1024) {
        unsigned int u = kb[g];
        if ((u >> 21) == sel1) atomicAdd(&hist[(u >> 10) & 2047u], 1);
    }
    __syncthreads();
    own = hist[2*t] + hist[2*t+1];
    part[t] = own;
    __syncthreads();
    for (int off = 1; off < 1024; off <<= 1) {
        int v = (t + off < 1024) ? part[t + off] : 0;
        __syncthreads();
        part[t] += v;
        __syncthreads();
    }
    want = s_want;
    __syncthreads();
    {
        int excl = part[t] - own;
        int hv = hist[2*t+1];
        if (excl < want && want <= excl + hv) { s_sel = 2*t+1; s_want = want - excl; }
        excl += hv;
        hv = hist[2*t];
        if (excl < want && want <= excl + hv) { s_sel = 2*t; s_want = want - excl; }
    }
    __syncthreads();
    unsigned int sel2 = (unsigned int)s_sel;
    unsigned int pref = (sel1 << 11) | sel2;

    // ---- pass 3: bits 9:0
    hist[t] = 0;
    __syncthreads();
    for (int g = t; g < G; g += 1024) {
        unsigned int u = kb[g];
        if ((u >> 10) == pref) atomicAdd(&hist[u & 1023u], 1);
    }
    __syncthreads();
    own = hist[t];
    part[t] = own;
    __syncthreads();
    for (int off = 1; off < 1024; off <<= 1) {
        int v = (t + off < 1024) ? part[t + off] : 0;
        __syncthreads();
        part[t] += v;
        __syncthreads();
    }
    want = s_want;
    __syncthreads();
    {
        int excl = part[t] - own;
        if (excl < want && want <= excl + own) {
            s_thr = (pref << 10) | (unsigned int)t;
            s_tneed = want - excl;
            s_alleq = (own == want - excl) ? 1 : 0;
        }
    }
    __syncthreads();
    unsigned int T = s_thr;
    int tn = s_tneed;
    bool ae = s_alleq != 0;

    // ---- accumulate over selected nodes
    float accA[16];
    #pragma unroll
    for (int c = 0; c < 16; ++c) accA[c] = 0.f;
    float accB = 0.f;
    for (int g = t; g < G; g += 1024) {
        unsigned int u = kb[g];
        bool take = (u > T);
        if (!take && u == T) {
            if (ae) take = true;
            else {  // rare tie path: rank among equals by node index
                int rank = 0;
                for (int gg = 0; gg < g; ++gg) rank += (kb[gg] == T) ? 1 : 0;
                take = (rank < tn);
            }
        }
        if (take) {
            unsigned int ub = (u & 0x80000000u) ? (u & 0x7FFFFFFFu) : ~u;
            float sv = __uint_as_float(ub);
            float tv = tanhf(sv);
            float tx = tv * x[(size_t)b * G + g];
            accB += tv * emb_b[g];
            const float4* row = (const float4*)(emb_w + (size_t)g * 16);
            float4 r0 = row[0], r1 = row[1], r2 = row[2], r3 = row[3];
            accA[0] = fmaf(tx, r0.x, accA[0]);  accA[1] = fmaf(tx, r0.y, accA[1]);
            accA[2] = fmaf(tx, r0.z, accA[2]);  accA[3] = fmaf(tx, r0.w, accA[3]);
            accA[4] = fmaf(tx, r1.x, accA[4]);  accA[5] = fmaf(tx, r1.y, accA[5]);
            accA[6] = fmaf(tx, r1.z, accA[6]);  accA[7] = fmaf(tx, r1.w, accA[7]);
            accA[8] = fmaf(tx, r2.x, accA[8]);  accA[9] = fmaf(tx, r2.y, accA[9]);
            accA[10] = fmaf(tx, r2.z, accA[10]); accA[11] = fmaf(tx, r2.w, accA[11]);
            accA[12] = fmaf(tx, r3.x, accA[12]); accA[13] = fmaf(tx, r3.y, accA[13]);
            accA[14] = fmaf(tx, r3.z, accA[14]); accA[15] = fmaf(tx, r3.w, accA[15]);
        }
    }
    #pragma unroll
    for (int off = 32; off; off >>= 1) {
        #pragma unroll
        for (int c = 0; c < 16; ++c) accA[c] += __shfl_down(accA[c], off);
        accB += __shfl_down(accB, off);
    }
    __syncthreads();                    // hist/part now reusable
    float* lred = (float*)hist;         // 16 waves x 17
    int w = t >> 6, lane = t & 63;
    if (lane == 0) {
        #pragma unroll
        for (int c = 0; c < 16; ++c) lred[w * 17 + c] = accA[c];
        lred[w * 17 + 16] = accB;
    }
    __syncthreads();
    float* sval = (float*)part;
    if (t < 17) {
        float s = 0.f;
        #pragma unroll
        for (int ww = 0; ww < 16; ++ww) s += lred[ww * 17 + t];
        sval[t] = s;
    }
    __syncthreads();
    if (t < 16) {
        float inv = 1.0f / (float)k;
        float bias = sval[16];
        float o = lin_b[t];
        #pragma unroll
        for (int c = 0; c < 16; ++c)
            o = fmaf((sval[c] + bias) * inv, lin_w[t * 16 + c], o);
        out[b * 16 + t] = o;
    }
}

extern "C" void kernel_launch(void* const* d_in, const int* in_sizes, int n_in,
                              void* d_out, int out_size, void* d_ws, size_t ws_size,
                              hipStream_t stream) {
    const float* x     = (const float*)d_in[0];
    const int*   ei    = (const int*)d_in[1];
    const float* emb_w = (const float*)d_in[3];
    const float* emb_b = (const float*)d_in[4];
    const float* gcn_w = (const float*)d_in[5];
    const float* gcn_b = (const float*)d_in[6];
    const float* lin_w = (const float*)d_in[7];
    const float* lin_b = (const float*)d_in[8];
    float* out = (float*)d_out;

    int N = in_sizes[0];          // 640000
    int E = in_sizes[1] / 2;      // 10240000
    int B = out_size / 16;        // 32
    int G = N / B;                // 20000
    int k = (G + 1) / 2;          // 10000
    int E_PER = E / B;            // 320000 base-graph edges

    const int* src = ei;          // first E_PER entries = base graph
    const int* dst = ei + E;

    int* wsI = (int*)d_ws;
    float* hws_t          = (float*)wsI;                 // N floats [g][b]
    unsigned int* key_bt  = (unsigned int*)(wsI + N);    // N uints  [b][g]
    int* pc               = wsI + 2 * (size_t)N;         // partial(32*GH) then csr(E_PER) — aliased
    int* rowptr           = pc + E_PER;                  // G+1
    int* wp               = rowptr + G + 1;              // G
    float* dis            = (float*)(wp + G);            // G
    float* ew_dot         = dis + G;                     // G

    k_edh<<<32, 1024, 0, stream>>>(emb_w, gcn_w, ew_dot, dst, pc, G, E_PER);
    k_scanhw<<<256, 1024, 0, stream>>>(pc, x, emb_b, ew_dot, gcn_w,
                                       rowptr, wp, dis, hws_t, G, N);
    k_fillsc<<<256, 1024, 0, stream>>>(src, dst, wp, pc, hws_t, dis, E_PER, N);
    k_spmm<<<(G + 63) / 64, 1024, 0, stream>>>(rowptr, pc, hws_t, dis, gcn_b, key_bt, G);
    k_sel<<<32, 1024, 0, stream>>>(key_bt, x, emb_w, emb_b, lin_w, lin_b, out, G, k);
}

// Round 8
// 118.264 us; speedup vs baseline: 3.1157x; 1.2827x over previous
//
#include <hip/hip_runtime.h>

// simpleGCN_SAGPOOL on MI355X (gfx950) — 6-dispatch pipeline.
// Measured facts driving the design (R0-R7):
//  - edge_index = 320K-edge base graph replicated B=32x (PyG batching).
//  - memory-side atomics ~32B each (R0) -> no bulk global fp32 atomics.
//  - per-dispatch overhead ~5-12us -> few dispatches, no cooperative sync
//    (grid.sync ~40us across 8 non-coherent XCD L2s, R6).
//  - single-block merge of 1.28MB = single-CU MLP-bound ~50us (R7) ->
//    merge must be grid-parallel; 1-block work capped at ~80KB.

#define GH 10000   // half bin-range for the 40KB LDS degree histogram

// K1 (32 blocks): chunk = bid>>1 edge range, half = bid&1 bin range.
// LDS partial degree hist (no memset, no global atomics) + ew_dot.
__global__ __launch_bounds__(1024) void k_edh(
    const float* __restrict__ emb_w, const float* __restrict__ gcn_w,
    float* __restrict__ ew_dot,
    const int* __restrict__ dst, int* __restrict__ partial, int G, int E_PER)
{
    __shared__ int h[GH];
    int tid = threadIdx.x, bid = blockIdx.x;
    int chunk = bid >> 1, half = bid & 1;
    int lo = half * GH;
    for (int i = tid; i < GH; i += 1024) h[i] = 0;
    __syncthreads();
    int EC = E_PER >> 4;
    int e0 = chunk * EC;
    int e1 = (chunk == 15) ? E_PER : e0 + EC;
    for (int e = e0 + tid; e < e1; e += 1024) {
        int d = dst[e] - lo;
        if ((unsigned)d < (unsigned)GH) atomicAdd(&h[d], 1);
    }
    {
        const float4* w = (const float4*)gcn_w;
        float4 w0 = w[0], w1 = w[1], w2 = w[2], w3 = w[3];
        int g = bid * 1024 + tid;
        if (g < G) {
            const float4* row = (const float4*)(emb_w + (size_t)g * 16);
            float4 r0 = row[0], r1 = row[1], r2 = row[2], r3 = row[3];
            ew_dot[g] = r0.x*w0.x + r0.y*w0.y + r0.z*w0.z + r0.w*w0.w
                      + r1.x*w1.x + r1.y*w1.y + r1.z*w1.z + r1.w*w1.w
                      + r2.x*w2.x + r2.y*w2.y + r2.z*w2.z + r2.w*w2.w
                      + r3.x*w3.x + r3.y*w3.y + r3.z*w3.z + r3.w*w3.w;
        }
    }
    __syncthreads();
    for (int i = tid; i < GH; i += 1024) partial[(size_t)bid * GH + i] = h[i];
}

// K2 (256 blocks): blocks 0..31 merge partials -> deg, dis (parallel,
// coalesced); blocks 32..255 compute UNSCALED hw via LDS-transpose tiles
// (coalesced x reads; dis folded into SpMM later).
__global__ __launch_bounds__(1024) void k_mergehw(
    const int* __restrict__ partial, const float* __restrict__ x,
    const float* __restrict__ emb_b, const float* __restrict__ ew_dot,
    const float* __restrict__ gcn_w,
    int* __restrict__ deg, float* __restrict__ dis,
    float* __restrict__ hws_t, int G, int N)
{
    int tid = threadIdx.x, bid = blockIdx.x;
    if (bid < 32) {
        // 625 bins per block; blocks 0-15 -> half 0, 16-31 -> half 1
        if (tid < 625) {
            int hf = bid >> 4;
            int off = (bid & 15) * 625 + tid;
            int d = 0;
            #pragma unroll
            for (int c = 0; c < 16; ++c)
                d += partial[(size_t)(2 * c + hf) * GH + off];
            int g = hf * GH + off;
            deg[g] = d;
            dis[g] = rsqrtf(1.0f + (float)d);
        }
    } else {
        __shared__ float tile[64][33];
        float sw = 0.f;
        #pragma unroll
        for (int c = 0; c < 16; ++c) sw += gcn_w[c];
        int nt = (G + 63) >> 6;
        for (int t = bid - 32; t < nt; t += 224) {
            int g0 = t << 6;
            __syncthreads();   // protect tile from previous iteration
            #pragma unroll
            for (int it = 0; it < 2; ++it) {
                int idx = it * 1024 + tid;
                int i = idx & 63, b = idx >> 6;
                int g = g0 + i;
                tile[i][b] = (g < G) ? x[(size_t)b * G + g] : 0.f;
            }
            __syncthreads();
            int r = tid >> 5, c = tid & 31;
            #pragma unroll
            for (int rr = 0; rr < 2; ++rr) {
                int g = g0 + r + rr * 32;
                if (g < G)
                    hws_t[(size_t)g * 32 + c] = ew_dot[g] * tile[r + rr * 32][c] + emb_b[g] * sw;
            }
        }
    }
}

// K3 (1 block): exclusive scan of deg -> rowptr, wp (int4 I/O, 80KB only)
__global__ __launch_bounds__(1024) void k_scan(
    const int* __restrict__ deg, int* __restrict__ rowptr, int* __restrict__ wp, int G)
{
    __shared__ int part[1024];
    int t = threadIdx.x;
    const int4* deg4 = (const int4*)deg;
    int per4 = (G >> 2) >> 10;            // G=20000 -> 5000 int4 -> not exact; handle rem
    // per-thread contiguous chunk of int4s
    int n4 = G >> 2;                      // 5000
    int beg = t * ((n4 + 1023) >> 10);    // ceil(5000/1024)=5 -> covers 5120
    int end = beg + ((n4 + 1023) >> 10); if (end > n4) end = n4;
    if (beg > n4) beg = n4;
    int4 v[5];
    int cnt = end - beg;
    int s = 0;
    for (int j = 0; j < cnt; ++j) {
        v[j] = deg4[beg + j];
        s += v[j].x + v[j].y + v[j].z + v[j].w;
    }
    part[t] = s;
    __syncthreads();
    for (int off = 1; off < 1024; off <<= 1) {
        int pv = (t >= off) ? part[t - off] : 0;
        __syncthreads();
        part[t] += pv;
        __syncthreads();
    }
    int run = part[t] - s;
    for (int j = 0; j < cnt; ++j) {
        int4 o;
        o.x = run;            run += v[j].x;
        o.y = run;            run += v[j].y;
        o.z = run;            run += v[j].z;
        o.w = run;            run += v[j].w;
        ((int4*)rowptr)[beg + j] = o;
        ((int4*)wp)[beg + j] = o;
    }
    if (t == 1023) rowptr[G] = part[1023];
    (void)per4;
}

// K4: fill dst-CSR (atomic int cursors in L2)
__global__ __launch_bounds__(1024) void k_fill(
    const int* __restrict__ src, const int* __restrict__ dst,
    int* __restrict__ wp, int* __restrict__ csr, int E_PER)
{
    int gt = blockIdx.x * 1024 + threadIdx.x;
    int gs = gridDim.x * 1024;
    for (int e = gt; e < E_PER; e += gs) {
        int d = dst[e];
        int pos = atomicAdd(&wp[d], 1);
        csr[pos] = src[e];
    }
}

// K5: SpMM (one wave per dst node, 64 nodes/block): score = dis[d] *
// (sum_in hw[s]*dis[s] + hw[d]*dis[d]) + gb; monotone key; LDS transpose
// so key_bt is [b][g] (coalesced per-graph reads in k_sel).
__global__ __launch_bounds__(1024) void k_spmm(
    const int* __restrict__ rowptr, const int* __restrict__ csr,
    const float* __restrict__ hws_t, const float* __restrict__ dis,
    const float* __restrict__ gcn_b, unsigned int* __restrict__ key_bt, int G)
{
    __shared__ unsigned int tile[64][33];
    int tid = threadIdx.x;
    int n0 = blockIdx.x * 64;
    int w = tid >> 6, lane = tid & 63, half = lane >> 5, b = lane & 31;
    float gb = gcn_b[0];
    #pragma unroll
    for (int r = 0; r < 4; ++r) {
        int node = n0 + r * 16 + w;
        if (node < G) {
            int beg = rowptr[node], end = rowptr[node + 1];
            float acc = 0.f;
            for (int e = beg + half; e < end; e += 2) {
                int s = csr[e];
                acc += hws_t[((size_t)s << 5) + b] * dis[s];
            }
            acc += __shfl_down(acc, 32);
            if (lane < 32) {
                float dd = dis[node];
                float sc = (acc + hws_t[((size_t)node << 5) + b] * dd) * dd + gb;
                unsigned int u = __float_as_uint(sc);
                u = (u & 0x80000000u) ? ~u : (u | 0x80000000u);
                tile[r * 16 + w][b] = u;
            }
        }
    }
    __syncthreads();
    for (int idx = tid; idx < 2048; idx += 1024) {
        int bb = idx >> 6, ln = idx & 63;
        if (n0 + ln < G) key_bt[(size_t)bb * G + n0 + ln] = tile[ln][bb];
    }
}

__device__ __forceinline__ int wave_suffix_incl(int v, int lane) {
    #pragma unroll
    for (int off = 1; off < 64; off <<= 1) {
        int o = __shfl_down(v, off);
        if (lane + off < 64) v += o;
    }
    return v;
}

// K6 (32 blocks, one per graph): exact k-th threshold via 3-level radix
// (bits 31:21, 20:10, 9:0) with 4-way privatized LDS hists + shuffle suffix
// scans, then accumulate tanh(s)*[x*emb_w, emb_b] + 16x16 linear.
__global__ __launch_bounds__(1024) void k_sel(
    const unsigned int* __restrict__ key_bt, const float* __restrict__ x,
    const float* __restrict__ emb_w, const float* __restrict__ emb_b,
    const float* __restrict__ lin_w, const float* __restrict__ lin_b,
    float* __restrict__ out, int G, int k)
{
    __shared__ int hist[4][2048];          // 32KB
    __shared__ int wtot[16], wsuf[16];
    __shared__ int s_sel, s_want;
    __shared__ unsigned int s_thr;
    __shared__ int s_tneed, s_alleq;
    int b = blockIdx.x, t = threadIdx.x;
    int lane = t & 63, w = t >> 6, cp = t >> 8;
    const unsigned int* kb = key_bt + (size_t)b * G;
    if (t == 0) s_want = k;

    // ---- pass 1: bits 31:21 (vectorized reads)
    for (int i = t; i < 8192; i += 1024) ((int*)hist)[i] = 0;
    __syncthreads();
    {
        const uint4* kb4 = (const uint4*)kb;
        int n4 = G >> 2;
        for (int i = t; i < n4; i += 1024) {
            uint4 u = kb4[i];
            atomicAdd(&hist[cp][u.x >> 21], 1);
            atomicAdd(&hist[cp][u.y >> 21], 1);
            atomicAdd(&hist[cp][u.z >> 21], 1);
            atomicAdd(&hist[cp][u.w >> 21], 1);
        }
    }
    __syncthreads();
    int hv0 = hist[0][2*t] + hist[1][2*t] + hist[2][2*t] + hist[3][2*t];
    int hv1 = hist[0][2*t+1] + hist[1][2*t+1] + hist[2][2*t+1] + hist[3][2*t+1];
    int own = hv0 + hv1;
    int sfx = wave_suffix_incl(own, lane);
    if (lane == 0) wtot[w] = sfx;
    __syncthreads();
    if (t < 16) {
        int v = wtot[t];
        #pragma unroll
        for (int off = 1; off < 16; off <<= 1) {
            int o = __shfl_down(v, off);
            if (t + off < 16) v += o;
        }
        wsuf[t] = v - wtot[t];
    }
    __syncthreads();
    int S = sfx + wsuf[w];                 // inclusive suffix over block
    int want = s_want;
    __syncthreads();
    {
        int excl = S - own;
        if (excl < want && want <= excl + hv1) { s_sel = 2*t+1; s_want = want - excl; }
        excl += hv1;
        if (excl < want && want <= excl + hv0) { s_sel = 2*t; s_want = want - excl; }
    }
    __syncthreads();
    unsigned int sel1 = (unsigned int)s_sel;

    // ---- pass 2: bits 20:10 among keys with top-11 == sel1
    for (int i = t; i < 8192; i += 1024) ((int*)hist)[i] = 0;
    __syncthreads();
    for (int g = t; g < G; g += 1024) {
        unsigned int u = kb[g];
        if ((u >> 21) == sel1) atomicAdd(&hist[cp][(u >> 10) & 2047u], 1);
    }
    __syncthreads();
    hv0 = hist[0][2*t] + hist[1][2*t] + hist[2][2*t] + hist[3][2*t];
    hv1 = hist[0][2*t+1] + hist[1][2*t+1] + hist[2][2*t+1] + hist[3][2*t+1];
    own = hv0 + hv1;
    sfx = wave_suffix_incl(own, lane);
    if (lane == 0) wtot[w] = sfx;
    __syncthreads();
    if (t < 16) {
        int v = wtot[t];
        #pragma unroll
        for (int off = 1; off < 16; off <<= 1) {
            int o = __shfl_down(v, off);
            if (t + off < 16) v += o;
        }
        wsuf[t] = v - wtot[t];
    }
    __syncthreads();
    S = sfx + wsuf[w];
    want = s_want;
    __syncthreads();
    {
        int excl = S - own;
        if (excl < want && want <= excl + hv1) { s_sel = 2*t+1; s_want = want - excl; }
        excl += hv1;
        if (excl < want && want <= excl + hv0) { s_sel = 2*t; s_want = want - excl; }
    }
    __syncthreads();
    unsigned int sel2 = (unsigned int)s_sel;
    unsigned int pref = (sel1 << 11) | sel2;

    // ---- pass 3: bits 9:0 among keys with top-22 == pref
    for (int i = t; i < 4096; i += 1024) ((int*)hist)[i] = 0;
    __syncthreads();
    for (int g = t; g < G; g += 1024) {
        unsigned int u = kb[g];
        if ((u >> 10) == pref) atomicAdd(&hist[cp][u & 1023u], 1);
    }
    __syncthreads();
    own = (t < 1024) ? hist[0][t] + hist[1][t] + hist[2][t] + hist[3][t] : 0;
    sfx = wave_suffix_incl(own, lane);
    if (lane == 0) wtot[w] = sfx;
    __syncthreads();
    if (t < 16) {
        int v = wtot[t];
        #pragma unroll
        for (int off = 1; off < 16; off <<= 1) {
            int o = __shfl_down(v, off);
            if (t + off < 16) v += o;
        }
        wsuf[t] = v - wtot[t];
    }
    __syncthreads();
    S = sfx + wsuf[w];
    want = s_want;
    __syncthreads();
    {
        int excl = S - own;
        if (excl < want && want <= excl + own) {
            s_thr = (pref << 10) | (unsigned int)t;
            s_tneed = want - excl;
            s_alleq = (own == want - excl) ? 1 : 0;
        }
    }
    __syncthreads();
    unsigned int T = s_thr;
    int tn = s_tneed;
    bool ae = s_alleq != 0;

    // ---- accumulate over selected nodes (all reads coalesced)
    float accA[16];
    #pragma unroll
    for (int c = 0; c < 16; ++c) accA[c] = 0.f;
    float accB = 0.f;
    for (int g = t; g < G; g += 1024) {
        unsigned int u = kb[g];
        bool take = (u > T);
        if (!take && u == T) {
            if (ae) take = true;
            else {  // rare tie path: rank among equals by node index
                int rank = 0;
                for (int gg = 0; gg < g; ++gg) rank += (kb[gg] == T) ? 1 : 0;
                take = (rank < tn);
            }
        }
        if (take) {
            unsigned int ub = (u & 0x80000000u) ? (u & 0x7FFFFFFFu) : ~u;
            float sv = __uint_as_float(ub);
            float tv = tanhf(sv);
            float tx = tv * x[(size_t)b * G + g];
            accB += tv * emb_b[g];
            const float4* row = (const float4*)(emb_w + (size_t)g * 16);
            float4 r0 = row[0], r1 = row[1], r2 = row[2], r3 = row[3];
            accA[0] = fmaf(tx, r0.x, accA[0]);  accA[1] = fmaf(tx, r0.y, accA[1]);
            accA[2] = fmaf(tx, r0.z, accA[2]);  accA[3] = fmaf(tx, r0.w, accA[3]);
            accA[4] = fmaf(tx, r1.x, accA[4]);  accA[5] = fmaf(tx, r1.y, accA[5]);
            accA[6] = fmaf(tx, r1.z, accA[6]);  accA[7] = fmaf(tx, r1.w, accA[7]);
            accA[8] = fmaf(tx, r2.x, accA[8]);  accA[9] = fmaf(tx, r2.y, accA[9]);
            accA[10] = fmaf(tx, r2.z, accA[10]); accA[11] = fmaf(tx, r2.w, accA[11]);
            accA[12] = fmaf(tx, r3.x, accA[12]); accA[13] = fmaf(tx, r3.y, accA[13]);
            accA[14] = fmaf(tx, r3.z, accA[14]); accA[15] = fmaf(tx, r3.w, accA[15]);
        }
    }
    #pragma unroll
    for (int off = 32; off; off >>= 1) {
        #pragma unroll
        for (int c = 0; c < 16; ++c) accA[c] += __shfl_down(accA[c], off);
        accB += __shfl_down(accB, off);
    }
    __syncthreads();
    float* lred = (float*)hist;           // 16 waves x 17
    if (lane == 0) {
        #pragma unroll
        for (int c = 0; c < 16; ++c) lred[w * 17 + c] = accA[c];
        lred[w * 17 + 16] = accB;
    }
    __syncthreads();
    float* sval = lred + 16 * 17;
    if (t < 17) {
        float s = 0.f;
        #pragma unroll
        for (int ww = 0; ww < 16; ++ww) s += lred[ww * 17 + t];
        sval[t] = s;
    }
    __syncthreads();
    if (t < 16) {
        float inv = 1.0f / (float)k;
        float bias = sval[16];
        float o = lin_b[t];
        #pragma unroll
        for (int c = 0; c < 16; ++c)
            o = fmaf((sval[c] + bias) * inv, lin_w[t * 16 + c], o);
        out[b * 16 + t] = o;
    }
}

extern "C" void kernel_launch(void* const* d_in, const int* in_sizes, int n_in,
                              void* d_out, int out_size, void* d_ws, size_t ws_size,
                              hipStream_t stream) {
    const float* x     = (const float*)d_in[0];
    const int*   ei    = (const int*)d_in[1];
    const float* emb_w = (const float*)d_in[3];
    const float* emb_b = (const float*)d_in[4];
    const float* gcn_w = (const float*)d_in[5];
    const float* gcn_b = (const float*)d_in[6];
    const float* lin_w = (const float*)d_in[7];
    const float* lin_b = (const float*)d_in[8];
    float* out = (float*)d_out;

    int N = in_sizes[0];          // 640000
    int E = in_sizes[1] / 2;      // 10240000
    int B = out_size / 16;        // 32
    int G = N / B;                // 20000
    int k = (G + 1) / 2;          // 10000
    int E_PER = E / B;            // 320000 base-graph edges

    const int* src = ei;          // first E_PER entries = base graph
    const int* dst = ei + E;

    int* wsI = (int*)d_ws;
    float* hws_t          = (float*)wsI;                 // N floats [g][b] (unscaled hw)
    unsigned int* key_bt  = (unsigned int*)(wsI + N);    // N uints  [b][g]
    int* pc               = wsI + 2 * (size_t)N;         // partial(32*GH) then csr(E_PER)
    int* deg              = pc + E_PER;                  // G
    int* rowptr           = deg + G;                     // G+1
    int* wp               = rowptr + G + 1;              // G
    float* dis            = (float*)(wp + G);            // G
    float* ew_dot         = dis + G;                     // G

    k_edh<<<32, 1024, 0, stream>>>(emb_w, gcn_w, ew_dot, dst, pc, G, E_PER);
    k_mergehw<<<256, 1024, 0, stream>>>(pc, x, emb_b, ew_dot, gcn_w,
                                        deg, dis, hws_t, G, N);
    k_scan<<<1, 1024, 0, stream>>>(deg, rowptr, wp, G);
    k_fill<<<256, 1024, 0, stream>>>(src, dst, wp, pc, E_PER);
    k_spmm<<<(G + 63) / 64, 1024, 0, stream>>>(rowptr, pc, hws_t, dis, gcn_b, key_bt, G);
    k_sel<<<32, 1024, 0, stream>>>(key_bt, x, emb_w, emb_b, lin_w, lin_b, out, G, k);
}